// Round 1
// baseline (242.048 us; speedup 1.0000x reference)
//
#include <hip/hip_runtime.h>
#include <stdint.h>

#define T_DIM 8192
#define B_DIM 4096
#define WORDS (T_DIM / 32)      // 256 word-rows
#define NSEG 16                 // segments along T (512 rows each)
#define CTILE 256               // columns per block
#define NEG_SLOPE 0.01f

// ---------------------------------------------------------------------------
// KA: read input (int32 0/1), pack bits into ws, compute per-segment per-col
// ones-count totals. Thread = 32 rows x 4 cols. 16 waves/block, wave == one
// word-row (rc is wave-uniform).
// ---------------------------------------------------------------------------
__global__ __launch_bounds__(1024) void ka_pack(const int* __restrict__ in,
                                                uint32_t* __restrict__ bits,
                                                int* __restrict__ segTotal) {
    const int c4  = threadIdx.x & 63;          // column-quad lane
    const int rc  = threadIdx.x >> 6;          // word-row within segment, 0..15
    const int col0 = blockIdx.x * CTILE + c4 * 4;
    const int wordrow = blockIdx.y * 16 + rc;  // global word row 0..255
    const int row0 = wordrow * 32;

    const int4* __restrict__ inv = (const int4*)in;
    uint32_t b0 = 0, b1 = 0, b2 = 0, b3 = 0;
#pragma unroll
    for (int r = 0; r < 32; ++r) {
        int4 v = inv[((size_t)(row0 + r) * B_DIM + col0) >> 2];
        b0 |= ((uint32_t)v.x & 1u) << r;
        b1 |= ((uint32_t)v.y & 1u) << r;
        b2 |= ((uint32_t)v.z & 1u) << r;
        b3 |= ((uint32_t)v.w & 1u) << r;
    }

    ((uint4*)bits)[((size_t)wordrow * B_DIM + col0) >> 2] = make_uint4(b0, b1, b2, b3);

    __shared__ int4 lds[16 * 64];
    lds[rc * 64 + c4] = make_int4(__popc(b0), __popc(b1), __popc(b2), __popc(b3));
    __syncthreads();

    if (rc == 0) {
        int4 s = make_int4(0, 0, 0, 0);
#pragma unroll
        for (int i = 0; i < 16; ++i) {
            int4 v = lds[i * 64 + c4];
            s.x += v.x; s.y += v.y; s.z += v.z; s.w += v.w;
        }
        ((int4*)segTotal)[((size_t)blockIdx.y * B_DIM + col0) >> 2] = s;
    }
}

// ---------------------------------------------------------------------------
// KB: reload packed bits (L2-resident, 4 MiB), reconstruct exact prefix count
// per row, emit leaky_relu((t+1-c)*d0 + c*d1) as float4 stores.
// ---------------------------------------------------------------------------
__global__ __launch_bounds__(1024) void kb_emit(const uint32_t* __restrict__ bits,
                                                const int* __restrict__ segTotal,
                                                const float* __restrict__ delta,
                                                float* __restrict__ out) {
    const int c4  = threadIdx.x & 63;
    const int rc  = threadIdx.x >> 6;
    const int col0 = blockIdx.x * CTILE + c4 * 4;
    const int seg = blockIdx.y;
    const int wordrow = seg * 16 + rc;
    const int row0 = wordrow * 32;

    uint4 w = ((const uint4*)bits)[((size_t)wordrow * B_DIM + col0) >> 2];

    __shared__ int4 lds[16 * 64];
    lds[rc * 64 + c4] = make_int4(__popc(w.x), __popc(w.y), __popc(w.z), __popc(w.w));

    // base = ones in all preceding segments (segTotal is tiny; L2/L3 hits)
    int c0 = 0, c1 = 0, c2 = 0, c3 = 0;
    for (int s = 0; s < seg; ++s) {
        int4 v = ((const int4*)segTotal)[((size_t)s * B_DIM + col0) >> 2];
        c0 += v.x; c1 += v.y; c2 += v.z; c3 += v.w;
    }
    __syncthreads();

    // + ones in preceding word-rows of this segment (rc is wave-uniform)
    for (int i = 0; i < rc; ++i) {
        int4 v = lds[i * 64 + c4];
        c0 += v.x; c1 += v.y; c2 += v.z; c3 += v.w;
    }

    const float d0 = delta[0];
    const float dd = delta[1] - d0;

    float4* __restrict__ outv = (float4*)out;
#pragma unroll
    for (int r = 0; r < 32; ++r) {
        const int t = row0 + r;
        const float tp = (float)(t + 1) * d0;
        c0 += (int)((w.x >> r) & 1u);
        c1 += (int)((w.y >> r) & 1u);
        c2 += (int)((w.z >> r) & 1u);
        c3 += (int)((w.w >> r) & 1u);
        float4 o;
        o.x = fmaf((float)c0, dd, tp);
        o.y = fmaf((float)c1, dd, tp);
        o.z = fmaf((float)c2, dd, tp);
        o.w = fmaf((float)c3, dd, tp);
        o.x = (o.x >= 0.0f) ? o.x : NEG_SLOPE * o.x;
        o.y = (o.y >= 0.0f) ? o.y : NEG_SLOPE * o.y;
        o.z = (o.z >= 0.0f) ? o.z : NEG_SLOPE * o.z;
        o.w = (o.w >= 0.0f) ? o.w : NEG_SLOPE * o.w;
        outv[((size_t)t * B_DIM + col0) >> 2] = o;
    }
}

extern "C" void kernel_launch(void* const* d_in, const int* in_sizes, int n_in,
                              void* d_out, int out_size, void* d_ws, size_t ws_size,
                              hipStream_t stream) {
    const int*   in    = (const int*)d_in[0];
    const float* delta = (const float*)d_in[1];
    float*       out   = (float*)d_out;

    uint32_t* bits     = (uint32_t*)d_ws;                                  // 4 MiB
    int*      segTotal = (int*)((char*)d_ws + (size_t)WORDS * B_DIM * 4);  // +256 KiB

    dim3 grid(B_DIM / CTILE, NSEG);   // (16, 16)
    dim3 block(1024);

    hipLaunchKernelGGL(ka_pack, grid, block, 0, stream, in, bits, segTotal);
    hipLaunchKernelGGL(kb_emit, grid, block, 0, stream, bits, segTotal, delta, out);
}